// Round 5
// baseline (235.387 us; speedup 1.0000x reference)
//
#include <hip/hip_runtime.h>
#include <math.h>

#define BATCH 4
#define LQ 2048
#define LK 2048
#define DIM 16
#define HEADS 2
#define DH 8
#define EPS 1e-5f

// ---------------- Kernel A: LayerNorm + Linear projection -----------------
__global__ __launch_bounds__(256) void ln_proj_kernel(
    const float* __restrict__ x,
    const float* __restrict__ g,
    const float* __restrict__ bln,
    const float* __restrict__ W,     // (16,16), torch [out,in]
    const float* __restrict__ bias,  // (16,)
    float* __restrict__ out,         // (B,H,L,DH)
    float* __restrict__ xn_out,      // may be null
    int nrows, int L, float scale)
{
    int r = blockIdx.x * blockDim.x + threadIdx.x;
    if (r >= nrows) return;

    float xv[16];
    const float4* xp = (const float4*)(x + (size_t)r * 16);
#pragma unroll
    for (int i = 0; i < 4; ++i) {
        float4 t = xp[i];
        xv[4*i+0] = t.x; xv[4*i+1] = t.y; xv[4*i+2] = t.z; xv[4*i+3] = t.w;
    }
    float m = 0.f;
#pragma unroll
    for (int i = 0; i < 16; ++i) m += xv[i];
    m *= (1.f / 16.f);
    float v = 0.f;
#pragma unroll
    for (int i = 0; i < 16; ++i) { float d = xv[i] - m; v += d * d; }
    v *= (1.f / 16.f);
    float rs = rsqrtf(v + EPS);

    float xn[16];
#pragma unroll
    for (int i = 0; i < 16; ++i) xn[i] = (xv[i] - m) * rs * g[i] + bln[i];

    if (xn_out) {
        float4* op = (float4*)(xn_out + (size_t)r * 16);
#pragma unroll
        for (int i = 0; i < 4; ++i) {
            float4 t; t.x = xn[4*i+0]; t.y = xn[4*i+1]; t.z = xn[4*i+2]; t.w = xn[4*i+3];
            op[i] = t;
        }
    }

    int b = r / L;
    int l = r - b * L;
#pragma unroll
    for (int j = 0; j < 16; ++j) {
        float acc = bias[j];
#pragma unroll
        for (int i = 0; i < 16; ++i) acc += xn[i] * W[j * 16 + i];
        acc *= scale;
        int h = j >> 3, d = j & 7;
        out[((((size_t)b * HEADS + h) * L) + l) * DH + d] = acc;
    }
}

// ---------------- Kernel B: full K/V panel in LDS, 16 rows/block ----------
// Structure (round 5): 1024 threads = 16 waves, one q-row per wave. Stage the
// ENTIRE 128KB K+V panel once, ONE barrier, then each wave streams its row
// with zero further synchronization. 1024 blocks, 4 serial per CU.
__device__ __forceinline__ float wave_sum(float v) {
#pragma unroll
    for (int off = 32; off > 0; off >>= 1) v += __shfl_xor(v, off);
    return v;
}

// launch_bounds(1024, 4): 4 waves/EU min -> VGPR cap 128 (kernel needs ~90).
__global__ __launch_bounds__(1024, 4) void attn_kernel(
    const float* __restrict__ Q,    // (B,H,LQ,DH) pre-scaled by 1/sqrt(dh)
    const float* __restrict__ K,    // (B,H,LK,DH)
    const float* __restrict__ V,    // (B,H,LK,DH)
    const float* __restrict__ w,    // (B,H,LQ,LK)
    const float* __restrict__ mask, // (B,H,LQ,LK)
    float* __restrict__ attn_out,   // (B,H,LQ,LK)
    float* __restrict__ ctx)        // (B,LQ,H,DH) == (B,LQ,16)
{
    // Consecutive lanes read consecutive float4 -> proven zero-conflict layout.
    __shared__ float4 K0[2048];  // K[c][0:4]
    __shared__ float4 K1[2048];  // K[c][4:8]
    __shared__ float4 V0[2048];
    __shared__ float4 V1[2048];  // total 128 KB

    const int t    = threadIdx.x;
    const int lane = t & 63;
    const int wid  = t >> 6;                 // 0..15, one q-row per wave
    const int bh   = blockIdx.x >> 7;        // 8 panels x 128 blocks
    const int qbase= (blockIdx.x & 127) << 4;
    const int q    = qbase + wid;
    const int rowid= (bh << 11) + q;
    const int h    = bh & (HEADS - 1);
    const int b    = bh >> 1;

    // ---- stage full K/V panel: each thread covers cols t and t+1024 ----
    {
        const float4* Kg = (const float4*)(K + (size_t)bh * LK * DH);
        const float4* Vg = (const float4*)(V + (size_t)bh * LK * DH);
        float4 ka0 = Kg[2 * t + 0],        ka1 = Kg[2 * t + 1];
        float4 kb0 = Kg[2048 + 2 * t + 0], kb1 = Kg[2048 + 2 * t + 1];
        float4 va0 = Vg[2 * t + 0],        va1 = Vg[2 * t + 1];
        float4 vb0 = Vg[2048 + 2 * t + 0], vb1 = Vg[2048 + 2 * t + 1];
        K0[t] = ka0;        K1[t] = ka1;
        K0[1024 + t] = kb0; K1[1024 + t] = kb1;
        V0[t] = va0;        V1[t] = va1;
        V0[1024 + t] = vb0; V1[1024 + t] = vb1;
    }

    const float* Qrow = Q + (size_t)rowid * DH;
    float qv[8];
#pragma unroll
    for (int i = 0; i < 8; ++i) qv[i] = Qrow[i];

    const float* wrow = w    + (size_t)rowid * LK;
    const float* mrow = mask + (size_t)rowid * LK;

    __syncthreads();   // the ONLY barrier

    float ebuf[32];
    float sum = 0.f;
    float c0=0,c1=0,c2=0,c3=0,c4=0,c5=0,c6=0,c7=0;

    // 4 groups of 8 cols/lane: 16 loads in flight per wave per group.
    for (int g = 0; g < 4; ++g) {
        float wv[8], mv[8];
#pragma unroll
        for (int j = 0; j < 8; ++j) {
            const int col = (((g << 3) + j) << 6) + lane;
            wv[j] = wrow[col];
            mv[j] = mrow[col];
        }
#pragma unroll
        for (int j = 0; j < 8; ++j) {
            const int i = (g << 3) + j;
            const int c = (i << 6) + lane;
            float4 k0 = K0[c], k1 = K1[c];
            float4 v0 = V0[c], v1 = V1[c];
            float s = qv[0]*k0.x + qv[1]*k0.y + qv[2]*k0.z + qv[3]*k0.w
                    + qv[4]*k1.x + qv[5]*k1.y + qv[6]*k1.z + qv[7]*k1.w
                    + wv[j] + mv[j];
            // softmax is shift-invariant; scores bounded ~|10|, fp32 exp is safe
            float e = __expf(s);
            ebuf[i] = e;
            sum += e;
            c0 += e * v0.x; c1 += e * v0.y; c2 += e * v0.z; c3 += e * v0.w;
            c4 += e * v1.x; c5 += e * v1.y; c6 += e * v1.z; c7 += e * v1.w;
        }
    }

    sum = wave_sum(sum);
    const float inv = 1.f / sum;

    // Nontemporal: 134MB attn stream must not evict w/mask from L3.
    float* arow = attn_out + (size_t)rowid * LK;
#pragma unroll
    for (int j = 0; j < 32; ++j) {
        __builtin_nontemporal_store(ebuf[j] * inv, arow + ((j << 6) + lane));
    }

    float cd[8] = {c0,c1,c2,c3,c4,c5,c6,c7};
#pragma unroll
    for (int d = 0; d < 8; ++d) cd[d] = wave_sum(cd[d]) * inv;
    if (lane == 0) {
        float* cp = ctx + ((((size_t)b * LQ + q) * HEADS) + h) * DH;
        float4 t0; t0.x = cd[0]; t0.y = cd[1]; t0.z = cd[2]; t0.w = cd[3];
        float4 t1; t1.x = cd[4]; t1.y = cd[5]; t1.z = cd[6]; t1.w = cd[7];
        ((float4*)cp)[0] = t0;
        ((float4*)cp)[1] = t1;
    }
}

// ---------------- Kernel C: output projection + residual ------------------
__global__ __launch_bounds__(256) void out_kernel(
    const float* __restrict__ ctx,  // (B,LQ,16)
    const float* __restrict__ Wo,   // (16,16)
    const float* __restrict__ bo,   // (16,)
    const float* __restrict__ q0,   // (B,LQ,16)
    float* __restrict__ out, int n)
{
    int gid = blockIdx.x * blockDim.x + threadIdx.x;
    if (gid >= n) return;
    int row = gid >> 4, j = gid & 15;
    const float* c = ctx + (size_t)row * 16;
    float acc = bo[j];
#pragma unroll
    for (int i = 0; i < 16; ++i) acc += c[i] * Wo[j * 16 + i];
    out[gid] = acc + q0[gid];
}

extern "C" void kernel_launch(void* const* d_in, const int* in_sizes, int n_in,
                              void* d_out, int out_size, void* d_ws, size_t ws_size,
                              hipStream_t stream) {
    const float* query = (const float*)d_in[0];
    const float* key_  = (const float*)d_in[1];
    const float* value = (const float*)d_in[2];
    const float* w     = (const float*)d_in[3];
    const float* mask  = (const float*)d_in[4];
    const float* ln_qg = (const float*)d_in[5];
    const float* ln_qb = (const float*)d_in[6];
    const float* ln_kg = (const float*)d_in[7];
    const float* ln_kb = (const float*)d_in[8];
    const float* ln_vg = (const float*)d_in[9];
    const float* ln_vb = (const float*)d_in[10];
    const float* Wq = (const float*)d_in[11];
    const float* bq = (const float*)d_in[12];
    const float* Wk = (const float*)d_in[13];
    const float* bk = (const float*)d_in[14];
    const float* Wv = (const float*)d_in[15];
    const float* bv = (const float*)d_in[16];
    const float* Wo = (const float*)d_in[17];
    const float* bo = (const float*)d_in[18];

    float* out  = (float*)d_out;                       // (B,LQ,16) first
    float* attn = out + (size_t)BATCH * LQ * DIM;      // then (B,H,LQ,LK)

    const size_t NE = (size_t)BATCH * LQ * DIM;        // 131072
    float* ws  = (float*)d_ws;
    float* Qb  = ws;            // (B,H,LQ,DH)
    float* Kb  = Qb + NE;       // (B,H,LK,DH)
    float* Vb  = Kb + NE;       // (B,H,LK,DH)
    float* q0  = Vb + NE;       // (B,LQ,16)
    float* ctx = q0 + NE;       // (B,LQ,16)

    const int nrows = BATCH * LQ;   // 8192
    const float qscale = 0.35355339059327373f;  // 1/sqrt(8)

    ln_proj_kernel<<<(nrows + 255) / 256, 256, 0, stream>>>(
        query, ln_qg, ln_qb, Wq, bq, Qb, q0, nrows, LQ, qscale);
    ln_proj_kernel<<<(nrows + 255) / 256, 256, 0, stream>>>(
        key_, ln_kg, ln_kb, Wk, bk, Kb, nullptr, nrows, LK, 1.0f);
    ln_proj_kernel<<<(nrows + 255) / 256, 256, 0, stream>>>(
        value, ln_vg, ln_vb, Wv, bv, Vb, nullptr, nrows, LK, 1.0f);

    // 1024 blocks: 8 bh panels x 128 blocks, 16 q-rows per block
    attn_kernel<<<BATCH * HEADS * LQ / 16, 1024, 0, stream>>>(
        Qb, Kb, Vb, w, mask, attn, ctx);

    out_kernel<<<((int)NE + 255) / 256, 256, 0, stream>>>(
        ctx, Wo, bo, q0, out, (int)NE);
}

// Round 6
// 95.297 us; speedup vs baseline: 2.4700x; 2.4700x over previous
//
#include <hip/hip_runtime.h>
#include <math.h>

#define BATCH 4
#define LQ 2048
#define LK 2048
#define DIM 16
#define HEADS 2
#define DH 8
#define EPS 1e-5f

typedef float fvec4 __attribute__((ext_vector_type(4)));

// ---------------- Kernel A: fused LayerNorm + Linear for q,k,v ------------
// grid covers 3*8192 rows; which = q/k/v selected per row range (no wave
// divergence: 8192 % 64 == 0). Saves two kernel launches (~8us).
__global__ __launch_bounds__(256) void ln_proj3_kernel(
    const float* __restrict__ xq, const float* __restrict__ xk,
    const float* __restrict__ xv,
    const float* __restrict__ gq, const float* __restrict__ bq_ln,
    const float* __restrict__ gk, const float* __restrict__ bk_ln,
    const float* __restrict__ gv, const float* __restrict__ bv_ln,
    const float* __restrict__ Wq, const float* __restrict__ bq,
    const float* __restrict__ Wk, const float* __restrict__ bk,
    const float* __restrict__ Wv, const float* __restrict__ bv,
    float* __restrict__ Qb, float* __restrict__ Kb, float* __restrict__ Vb,
    float* __restrict__ q0)
{
    const int gid = blockIdx.x * blockDim.x + threadIdx.x;
    const int which = gid >> 13;          // 0=q 1=k 2=v
    const int r     = gid & 8191;

    const float* x; const float* g; const float* bl;
    const float* W; const float* bb; float* outp; float scale;
    if (which == 0)      { x = xq; g = gq; bl = bq_ln; W = Wq; bb = bq; outp = Qb; scale = 0.35355339059327373f; }
    else if (which == 1) { x = xk; g = gk; bl = bk_ln; W = Wk; bb = bk; outp = Kb; scale = 1.0f; }
    else                 { x = xv; g = gv; bl = bv_ln; W = Wv; bb = bv; outp = Vb; scale = 1.0f; }

    float xv16[16];
    const float4* xp = (const float4*)(x + (size_t)r * 16);
#pragma unroll
    for (int i = 0; i < 4; ++i) {
        float4 t = xp[i];
        xv16[4*i+0] = t.x; xv16[4*i+1] = t.y; xv16[4*i+2] = t.z; xv16[4*i+3] = t.w;
    }
    float m = 0.f;
#pragma unroll
    for (int i = 0; i < 16; ++i) m += xv16[i];
    m *= (1.f / 16.f);
    float var = 0.f;
#pragma unroll
    for (int i = 0; i < 16; ++i) { float d = xv16[i] - m; var += d * d; }
    var *= (1.f / 16.f);
    float rs = rsqrtf(var + EPS);

    float xn[16];
#pragma unroll
    for (int i = 0; i < 16; ++i) xn[i] = (xv16[i] - m) * rs * g[i] + bl[i];

    if (which == 0) {
        float4* op = (float4*)(q0 + (size_t)r * 16);
#pragma unroll
        for (int i = 0; i < 4; ++i) {
            float4 t; t.x = xn[4*i+0]; t.y = xn[4*i+1]; t.z = xn[4*i+2]; t.w = xn[4*i+3];
            op[i] = t;
        }
    }

    const int b = r >> 11;            // r / 2048
    const int l = r & 2047;
#pragma unroll
    for (int j = 0; j < 16; ++j) {
        float acc = bb[j];
#pragma unroll
        for (int i = 0; i < 16; ++i) acc += xn[i] * W[j * 16 + i];
        acc *= scale;
        int h = j >> 3, d = j & 7;
        outp[((((size_t)b * HEADS + h) * 2048) + l) * DH + d] = acc;
    }
}

// ---------------- Kernel B: SoA LDS K/V, float4 streams, 8 rows/block -----
__device__ __forceinline__ float wave_sum(float v) {
#pragma unroll
    for (int off = 32; off > 0; off >>= 1) v += __shfl_xor(v, off);
    return v;
}

// launch_bounds(512,2) is the proven no-spill config (VGPR cap >=128).
// (512,4)/(1024,4) both forced a 64-VGPR cap and spilled ebuf (r3, r5).
__global__ __launch_bounds__(512, 2) void attn_kernel(
    const float* __restrict__ Q,    // (B,H,LQ,DH) pre-scaled by 1/sqrt(dh)
    const float* __restrict__ K,    // (B,H,LK,DH)
    const float* __restrict__ V,    // (B,H,LK,DH)
    const float* __restrict__ w,    // (B,H,LQ,LK)
    const float* __restrict__ mask, // (B,H,LQ,LK)
    float* __restrict__ attn_out,   // (B,H,LQ,LK)
    float* __restrict__ ctx)        // (B,LQ,H,DH) == (B,LQ,16)
{
    // SoA: Ks[d][col], Vs[d][col] for a 1024-col chunk. 64 KB total.
    // Lane reads float4 at col=lane*4 -> contiguous 1024B/wave, conflict-free.
    __shared__ float Ks[8][1024];
    __shared__ float Vs[8][1024];

    const int t    = threadIdx.x;
    const int lane = t & 63;
    const int wid  = t >> 6;                 // 0..7, one q-row per wave
    const int bh   = blockIdx.x >> 8;        // 8 panels x 256 blocks
    const int qbase= (blockIdx.x & 255) << 3;
    const int q    = qbase + wid;
    const int rowid= (bh << 11) + q;
    const int h    = bh & (HEADS - 1);
    const int b    = bh >> 1;

    const float* Qrow = Q + (size_t)rowid * DH;
    float qv[8];
#pragma unroll
    for (int i = 0; i < 8; ++i) qv[i] = Qrow[i];

    const fvec4* Kg = (const fvec4*)(K + (size_t)bh * LK * DH);
    const fvec4* Vg = (const fvec4*)(V + (size_t)bh * LK * DH);
    const float* wrow = w    + (size_t)rowid * LK;
    const float* mrow = mask + (size_t)rowid * LK;

    fvec4 ebuf[8];
    float sum = 0.f;
    float cd[8] = {0,0,0,0,0,0,0,0};

#pragma unroll
    for (int chunk = 0; chunk < 2; ++chunk) {
        if (chunk) __syncthreads();
        // ---- stage 1024 cols SoA: each thread scatters cols t and t+512 ----
        {
            const int gbase = chunk << 10;
#pragma unroll
            for (int rr = 0; rr < 2; ++rr) {
                const int c = t + (rr << 9);
                fvec4 k0 = Kg[(size_t)(gbase + c) * 2 + 0];
                fvec4 k1 = Kg[(size_t)(gbase + c) * 2 + 1];
                fvec4 v0 = Vg[(size_t)(gbase + c) * 2 + 0];
                fvec4 v1 = Vg[(size_t)(gbase + c) * 2 + 1];
                Ks[0][c] = k0.x; Ks[1][c] = k0.y; Ks[2][c] = k0.z; Ks[3][c] = k0.w;
                Ks[4][c] = k1.x; Ks[5][c] = k1.y; Ks[6][c] = k1.z; Ks[7][c] = k1.w;
                Vs[0][c] = v0.x; Vs[1][c] = v0.y; Vs[2][c] = v0.z; Vs[3][c] = v0.w;
                Vs[4][c] = v1.x; Vs[5][c] = v1.y; Vs[6][c] = v1.z; Vs[7][c] = v1.w;
            }
        }
        __syncthreads();
        // ---- compute: 4 groups of 4 consecutive cols per lane ----
#pragma unroll
        for (int i = 0; i < 4; ++i) {
            const int cbase = (i << 8) + (lane << 2);        // within chunk
            const int col   = (chunk << 10) + cbase;
            fvec4 wv = __builtin_nontemporal_load((const fvec4*)(wrow + col));
            fvec4 mv = __builtin_nontemporal_load((const fvec4*)(mrow + col));
            fvec4 s = wv + mv;
#pragma unroll
            for (int d = 0; d < 8; ++d) {
                fvec4 k4 = *(const fvec4*)&Ks[d][cbase];
                s += qv[d] * k4;
            }
            // softmax is shift-invariant; scores bounded ~|10|, fp32 exp safe
            fvec4 e;
            e.x = __expf(s.x); e.y = __expf(s.y); e.z = __expf(s.z); e.w = __expf(s.w);
            ebuf[(chunk << 2) + i] = e;
            sum += e.x + e.y + e.z + e.w;
#pragma unroll
            for (int d = 0; d < 8; ++d) {
                fvec4 v4 = *(const fvec4*)&Vs[d][cbase];
                cd[d] += e.x * v4.x + e.y * v4.y + e.z * v4.z + e.w * v4.w;
            }
        }
    }

    sum = wave_sum(sum);
    const float inv = 1.f / sum;

    // float4 nontemporal stores: don't evict w/mask stream from L2/L3.
    float* arow = attn_out + (size_t)rowid * LK;
#pragma unroll
    for (int j = 0; j < 8; ++j) {
        const int col = ((j >> 2) << 10) + ((j & 3) << 8) + (lane << 2);
        __builtin_nontemporal_store(ebuf[j] * inv, (fvec4*)(arow + col));
    }

#pragma unroll
    for (int d = 0; d < 8; ++d) cd[d] = wave_sum(cd[d]) * inv;
    if (lane == 0) {
        float* cp = ctx + ((((size_t)b * LQ + q) * HEADS) + h) * DH;
        fvec4 t0; t0.x = cd[0]; t0.y = cd[1]; t0.z = cd[2]; t0.w = cd[3];
        fvec4 t1; t1.x = cd[4]; t1.y = cd[5]; t1.z = cd[6]; t1.w = cd[7];
        ((fvec4*)cp)[0] = t0;
        ((fvec4*)cp)[1] = t1;
    }
}

// ---------------- Kernel C: output projection + residual ------------------
__global__ __launch_bounds__(256) void out_kernel(
    const float* __restrict__ ctx,  // (B,LQ,16)
    const float* __restrict__ Wo,   // (16,16)
    const float* __restrict__ bo,   // (16,)
    const float* __restrict__ q0,   // (B,LQ,16)
    float* __restrict__ out, int n)
{
    int gid = blockIdx.x * blockDim.x + threadIdx.x;
    if (gid >= n) return;
    int row = gid >> 4, j = gid & 15;
    const float* c = ctx + (size_t)row * 16;
    float acc = bo[j];
#pragma unroll
    for (int i = 0; i < 16; ++i) acc += c[i] * Wo[j * 16 + i];
    out[gid] = acc + q0[gid];
}

extern "C" void kernel_launch(void* const* d_in, const int* in_sizes, int n_in,
                              void* d_out, int out_size, void* d_ws, size_t ws_size,
                              hipStream_t stream) {
    const float* query = (const float*)d_in[0];
    const float* key_  = (const float*)d_in[1];
    const float* value = (const float*)d_in[2];
    const float* w     = (const float*)d_in[3];
    const float* mask  = (const float*)d_in[4];
    const float* ln_qg = (const float*)d_in[5];
    const float* ln_qb = (const float*)d_in[6];
    const float* ln_kg = (const float*)d_in[7];
    const float* ln_kb = (const float*)d_in[8];
    const float* ln_vg = (const float*)d_in[9];
    const float* ln_vb = (const float*)d_in[10];
    const float* Wq = (const float*)d_in[11];
    const float* bq = (const float*)d_in[12];
    const float* Wk = (const float*)d_in[13];
    const float* bk = (const float*)d_in[14];
    const float* Wv = (const float*)d_in[15];
    const float* bv = (const float*)d_in[16];
    const float* Wo = (const float*)d_in[17];
    const float* bo = (const float*)d_in[18];

    float* out  = (float*)d_out;                       // (B,LQ,16) first
    float* attn = out + (size_t)BATCH * LQ * DIM;      // then (B,H,LQ,LK)

    const size_t NE = (size_t)BATCH * LQ * DIM;        // 131072
    float* ws  = (float*)d_ws;
    float* Qb  = ws;            // (B,H,LQ,DH)
    float* Kb  = Qb + NE;       // (B,H,LK,DH)
    float* Vb  = Kb + NE;       // (B,H,LK,DH)
    float* q0  = Vb + NE;       // (B,LQ,16)
    float* ctx = q0 + NE;       // (B,LQ,16)

    // 3*8192 rows in one launch
    ln_proj3_kernel<<<(3 * 8192) / 256, 256, 0, stream>>>(
        query, key_, value,
        ln_qg, ln_qb, ln_kg, ln_kb, ln_vg, ln_vb,
        Wq, bq, Wk, bk, Wv, bv,
        Qb, Kb, Vb, q0);

    // 2048 blocks: 8 bh panels x 256 blocks, 8 q-rows per block
    attn_kernel<<<BATCH * HEADS * LQ / 8, 512, 0, stream>>>(
        Qb, Kb, Vb, w, mask, attn, ctx);

    out_kernel<<<((int)NE + 255) / 256, 256, 0, stream>>>(
        ctx, Wo, bo, q0, out, (int)NE);
}